// Round 13
// baseline (554.454 us; speedup 1.0000x reference)
//
#include <hip/hip_runtime.h>
#include <hip/hip_fp16.h>
#include <math.h>
#include <stdint.h>

#define DD 64
#define NRG 512        // nodes per range (9 bits)
#define BB  128        // binning blocks

using f16x8 = __attribute__((ext_vector_type(8))) _Float16;
using f32x4 = __attribute__((ext_vector_type(4))) float;

static inline int divup(int a, int b){ return (a + b - 1) / b; }

// ---------------------------------------------------------------------------
// CSR build, zero global atomics (R9: memory-side RMW ~150ns/op on hot words).
// ---------------------------------------------------------------------------
__global__ __launch_bounds__(256) void bin_k(
    const int* __restrict__ edg, int E, int per, int nr, int cap,
    unsigned int* __restrict__ bufc, unsigned short* __restrict__ bufr,
    int* __restrict__ cntc, int* __restrict__ cntr)
{
  extern __shared__ int cur[];            // [nr] col cursors | [nr] row cursors
  int* curc = cur;
  int* curr = cur + nr;
  const int b = blockIdx.x, t = threadIdx.x;
  for (int i = t; i < 2 * nr; i += 256) cur[i] = 0;
  __syncthreads();
  const int e0 = b * per;
  const int e1 = (e0 + per < E) ? e0 + per : E;
  unsigned int* mybufc = bufc + (size_t)b * nr * cap;
  unsigned short* mybufr = bufr + (size_t)b * nr * cap;
  for (int e = e0 + t; e < e1; e += 256){
    int r = edg[e];
    int c = edg[E + e];
    int rg = c >> 9;
    int p = atomicAdd(&curc[rg], 1);      // LDS atomic
    if (p < cap) mybufc[rg * cap + p] = ((unsigned int)r << 9) | (unsigned int)(c & 511);
    int rr = r >> 9;
    int q = atomicAdd(&curr[rr], 1);      // LDS atomic
    if (q < cap) mybufr[rr * cap + q] = (unsigned short)(r & 511);
  }
  __syncthreads();
  for (int i = t; i < nr; i += 256){
    int vc = curc[i]; cntc[b * nr + i] = vc < cap ? vc : cap;
    int vr = curr[i]; cntr[b * nr + i] = vr < cap ? vr : cap;
  }
}

// --- per-range histograms + in-LDS exclusive scan -> locoff, rtot, dinv ---
__global__ __launch_bounds__(256) void cnt2b_k(
    const unsigned int* __restrict__ bufc, const unsigned short* __restrict__ bufr,
    const int* __restrict__ cntc, const int* __restrict__ cntr,
    int nb, int nr, int cap,
    int* __restrict__ locoff, int* __restrict__ rtot, float* __restrict__ dinv, int N)
{
  __shared__ int lhc[NRG];
  __shared__ int lhr[NRG];
  __shared__ int lcc[BB];
  __shared__ int lcr[BB];
  __shared__ int ps[256];
  const int rg = blockIdx.x, t = threadIdx.x;
  for (int i = t; i < NRG; i += 256){ lhc[i] = 0; lhr[i] = 0; }
  for (int i = t; i < nb; i += 256){ lcc[i] = cntc[i * nr + rg]; lcr[i] = cntr[i * nr + rg]; }
  __syncthreads();
  const int wv = t >> 6, lane = t & 63;
  for (int b = wv; b < nb; b += 4){
    const unsigned int* buf = bufc + ((size_t)b * nr + rg) * cap;
    int cnt = lcc[b];
    for (int i = lane; i < cnt; i += 64) atomicAdd(&lhc[buf[i] & 511], 1);
    const unsigned short* bufR = bufr + ((size_t)b * nr + rg) * cap;
    int cntR = lcr[b];
    for (int i = lane; i < cntR; i += 64) atomicAdd(&lhr[bufR[i]], 1);
  }
  __syncthreads();
  for (int i = t; i < NRG; i += 256){
    int node = rg * NRG + i;
    if (node < N) dinv[node] = rsqrtf((float)lhr[i] + 2.0f);
  }
  int v0 = lhc[2 * t], v1 = lhc[2 * t + 1];
  int s = v0 + v1;
  ps[t] = s; __syncthreads();
  for (int off = 1; off < 256; off <<= 1){
    int x = (t >= off) ? ps[t - off] : 0;
    __syncthreads();
    ps[t] += x;
    __syncthreads();
  }
  int excl = ps[t] - s;
  int n0 = rg * NRG + 2 * t;
  if (n0 < N)     locoff[n0]     = excl;
  if (n0 + 1 < N) locoff[n0 + 1] = excl + v0;
  if (t == 255) rtot[rg] = ps[255];
}

__global__ void rscan_k(const int* __restrict__ rtot, int* __restrict__ rbase,
                        int* __restrict__ offsets, int nr, int E, int N){
  __shared__ int sh[256];
  int t = threadIdx.x;
  int v = (t < nr) ? rtot[t] : 0;
  sh[t] = v; __syncthreads();
  for (int off = 1; off < 256; off <<= 1){
    int x = (t >= off) ? sh[t - off] : 0;
    __syncthreads();
    sh[t] += x;
    __syncthreads();
  }
  if (t < nr) rbase[t] = sh[t] - v;
  if (t == 0) offsets[N] = E;
}

// --- per-range CSR scatter: LDS cursors = rbase+locoff; writes offsets[] ---
__global__ __launch_bounds__(256) void scat_k(
    const unsigned int* __restrict__ bufc, const int* __restrict__ cntc,
    int nb, int nr, int cap, const int* __restrict__ locoff,
    const int* __restrict__ rbase,
    int* __restrict__ offsets, int* __restrict__ csr_src, int N)
{
  __shared__ int loff[NRG];
  __shared__ int lcc[BB];
  const int rg = blockIdx.x, t = threadIdx.x;
  const int base = rbase[rg];
  for (int i = t; i < NRG; i += 256){
    int node = rg * NRG + i;
    if (node < N){
      int o = base + locoff[node];
      loff[i] = o;
      offsets[node] = o;
    } else loff[i] = 0;
  }
  for (int i = t; i < nb; i += 256) lcc[i] = cntc[i * nr + rg];
  __syncthreads();
  const int wv = t >> 6, lane = t & 63;
  for (int b = wv; b < nb; b += 4){
    const unsigned int* buf = bufc + ((size_t)b * nr + rg) * cap;
    int cnt = lcc[b];
    for (int i = lane; i < cnt; i += 64){
      unsigned int v = buf[i];
      int p = atomicAdd(&loff[v & 511], 1);   // LDS atomic
      csr_src[p] = (int)(v >> 9);
    }
  }
}

// --- pack layer-0: XH[n][j] = dinv[n]*(x, h) fp16 ---
__global__ void pack0_k(const float* __restrict__ X, const float* __restrict__ H,
                        const float* __restrict__ dinv, __half2* __restrict__ XH, int total){
  int i = blockIdx.x * 256 + threadIdx.x;
  if (i < total){
    float dv = dinv[i >> 6];
    __half2 v;
    v.x = __float2half_rn(dv * X[i]);
    v.y = __float2half_rn(dv * H[i]);
    XH[i] = v;
  }
}

// --- pack weights into MFMA B-fragment order + fused biases (see R8) ---
__global__ void packb_k(const float* __restrict__ Wxz, const float* __restrict__ Whz,
                        const float* __restrict__ Wxr, const float* __restrict__ Whr,
                        const float* __restrict__ Wxh, const float* __restrict__ Whh,
                        const float* __restrict__ bxz, const float* __restrict__ bhz,
                        const float* __restrict__ bxr, const float* __restrict__ bhr,
                        const float* __restrict__ bxh, const float* __restrict__ bhh,
                        _Float16* __restrict__ Bg, _Float16* __restrict__ Bo,
                        float* __restrict__ biasg, int L){
  const int PER = 24576 + 4096 + 192;
  int tid = blockIdx.x * 256 + threadIdx.x;
  if (tid >= L * PER) return;
  int l = tid / PER, r = tid % PER;
  if (r < 24576){
    int q = r;
    int s = q & 7, lane = (q >> 3) & 63, ks = (q >> 9) & 3, jt = q >> 11;
    int k = ks * 32 + (lane >> 4) * 8 + s;
    int b = jt >> 2;
    int j = (jt & 3) * 16 + (lane & 15);
    const float* Wx = (b == 0) ? Wxz : (b == 1) ? Wxr : Wxh;
    const float* Wh = (b == 0) ? Whz : Whr;
    float v;
    if (k < 64) v = Wx[(size_t)l * 4096 + k * 64 + j];
    else        v = (b == 2) ? 0.0f : Wh[(size_t)l * 4096 + (k - 64) * 64 + j];
    Bg[(size_t)l * 24576 + q] = (_Float16)v;
  } else if (r < 24576 + 4096){
    int q = r - 24576;
    int s = q & 7, lane = (q >> 3) & 63, ks = (q >> 9) & 1, jt = q >> 10;
    int k = ks * 32 + (lane >> 4) * 8 + s;
    int j = jt * 16 + (lane & 15);
    Bo[(size_t)l * 4096 + q] = (_Float16)Whh[(size_t)l * 4096 + k * 64 + j];
  } else {
    int j = r - (24576 + 4096);
    int b = j >> 6, jj = j & 63;
    float v = (b == 0) ? bxz[l * 64 + jj] + bhz[l * 64 + jj]
            : (b == 1) ? bxr[l * 64 + jj] + bhr[l * 64 + jj]
                       : bxh[l * 64 + jj] + bhh[l * 64 + jj];
    biasg[l * 192 + j] = v;
  }
}

// --- aggregation of pre-scaled (x,h) rows, unroll 8 ---
__global__ void agg2_k(const __half2* __restrict__ XH,
                       const int* __restrict__ offsets, const int* __restrict__ src,
                       const float* __restrict__ dinv,
                       _Float16* __restrict__ AXAH, int N){
  int wid = (blockIdx.x * blockDim.x + threadIdx.x) >> 6;
  int lane = threadIdx.x & 63;
  if (wid >= N) return;
  float dv = dinv[wid];
  size_t me = (size_t)wid * DD + lane;
  float2 sf = __half22float2(XH[me]);
  float ax[8], ah[8];
  #pragma unroll
  for (int j = 0; j < 8; j++){ ax[j] = 0.0f; ah[j] = 0.0f; }
  int s0 = offsets[wid], s1 = offsets[wid + 1];
  int e = s0;
  for (; e + 8 <= s1; e += 8){
    int sn[8];
    float2 f[8];
    #pragma unroll
    for (int j = 0; j < 8; j++) sn[j] = src[e + j];
    #pragma unroll
    for (int j = 0; j < 8; j++) f[j] = __half22float2(XH[(size_t)sn[j] * DD + lane]);
    #pragma unroll
    for (int j = 0; j < 8; j++){
      ax[j] += f[j].x;
      ah[j] += f[j].y;
    }
  }
  for (; e < s1; ++e){
    float2 fa = __half22float2(XH[(size_t)src[e] * DD + lane]);
    ax[0] += fa.x;
    ah[0] += fa.y;
  }
  float axs = ((ax[0] + ax[1]) + (ax[2] + ax[3])) + ((ax[4] + ax[5]) + (ax[6] + ax[7]));
  float ahs = ((ah[0] + ah[1]) + (ah[2] + ah[3])) + ((ah[4] + ah[5]) + (ah[6] + ah[7]));
  size_t o = (size_t)wid * 128 + lane;
  AXAH[o]      = (_Float16)(dv * (axs + 2.0f * sf.x));
  AXAH[o + 64] = (_Float16)(dv * (ahs + 2.0f * sf.y));
}

// --- aggregation of pre-scaled r*h rows, unroll 8 ---
__global__ void agg1_k(const _Float16* __restrict__ RH,
                       const int* __restrict__ offsets, const int* __restrict__ src,
                       const float* __restrict__ dinv,
                       _Float16* __restrict__ Arh, int N){
  int wid = (blockIdx.x * blockDim.x + threadIdx.x) >> 6;
  int lane = threadIdx.x & 63;
  if (wid >= N) return;
  float dv = dinv[wid];
  size_t me = (size_t)wid * DD + lane;
  float selfv = (float)RH[me];
  float ax[8];
  #pragma unroll
  for (int j = 0; j < 8; j++) ax[j] = 0.0f;
  int s0 = offsets[wid], s1 = offsets[wid + 1];
  int e = s0;
  for (; e + 8 <= s1; e += 8){
    int sn[8];
    float f[8];
    #pragma unroll
    for (int j = 0; j < 8; j++) sn[j] = src[e + j];
    #pragma unroll
    for (int j = 0; j < 8; j++) f[j] = (float)RH[(size_t)sn[j] * DD + lane];
    #pragma unroll
    for (int j = 0; j < 8; j++) ax[j] += f[j];
  }
  for (; e < s1; ++e){
    ax[0] += (float)RH[(size_t)src[e] * DD + lane];
  }
  float axs = ((ax[0] + ax[1]) + (ax[2] + ax[3])) + ((ax[4] + ax[5]) + (ax[6] + ax[7]));
  Arh[me] = (_Float16)(dv * (axs + 2.0f * selfv));
}

// ---------------------------------------------------------------------------
// MFMA gate kernel v3: C(N x 192) = AXAH @ Bg + bias.
// zb, t1, zh(=z*h) stored in FRAGMENT layout (fo = gtid*32, 64B contiguous
// per thread) — consumed by outm at identical thread mapping.  rhb stays in
// node layout (agg1 gathers it).
// ---------------------------------------------------------------------------
__global__ __launch_bounds__(256) void gatem_k(
    const _Float16* __restrict__ AXAH, const float* __restrict__ Hh,
    const float* __restrict__ dinv,
    const _Float16* __restrict__ Bg, const float* __restrict__ biasg,
    _Float16* __restrict__ zbf, _Float16* __restrict__ zhf_g,
    _Float16* __restrict__ rhb, _Float16* __restrict__ t1f, int N)
{
  const int lane = threadIdx.x & 63;
  const int wv   = threadIdx.x >> 6;
  const long nbase = ((long)blockIdx.x * 4 + wv) * 32;
  if (nbase >= N) return;
  const int m  = lane & 15;
  const int kb = lane >> 4;

  f32x4 acc[2][12];
  #pragma unroll
  for (int jt = 0; jt < 12; jt++){
    float bv = biasg[jt * 16 + m];
    f32x4 b4 = {bv, bv, bv, bv};
    acc[0][jt] = b4;
    acc[1][jt] = b4;
  }

  #pragma unroll 1
  for (int ks = 0; ks < 4; ks++){
    f16x8 af0, af1;
    {
      long r0 = nbase + m;           if (r0 >= N) r0 = N - 1;
      long r1 = nbase + 16 + m;      if (r1 >= N) r1 = N - 1;
      af0 = *(const f16x8*)(AXAH + (size_t)r0 * 128 + ks * 32 + kb * 8);
      af1 = *(const f16x8*)(AXAH + (size_t)r1 * 128 + ks * 32 + kb * 8);
    }
    #pragma unroll
    for (int jt = 0; jt < 12; jt++){
      f16x8 bf = *(const f16x8*)(Bg + ((size_t)(jt * 4 + ks) * 64 + lane) * 8);
      acc[0][jt] = __builtin_amdgcn_mfma_f32_16x16x32_f16(af0, bf, acc[0][jt], 0, 0, 0);
      acc[1][jt] = __builtin_amdgcn_mfma_f32_16x16x32_f16(af1, bf, acc[1][jt], 0, 0, 0);
    }
  }

  _Float16 zf[32], tf[32], zhf[32];
  #pragma unroll
  for (int mt = 0; mt < 2; mt++){
    #pragma unroll
    for (int i = 0; i < 4; i++){
      long row = nbase + mt * 16 + kb * 4 + i;
      long rc = row < N ? row : N - 1;
      float dvr = dinv[rc];
      #pragma unroll
      for (int jq = 0; jq < 4; jq++){
        int j = jq * 16 + m;
        size_t o = (size_t)rc * 64 + j;
        float hv = Hh[o];
        float z  = 1.0f / (1.0f + __expf(-acc[mt][jq][i]));
        float rr = 1.0f / (1.0f + __expf(-acc[mt][4 + jq][i]));
        const int idx = mt * 16 + jq * 4 + i;
        zf[idx]  = (_Float16)z;
        zhf[idx] = (_Float16)(z * hv);
        tf[idx]  = (_Float16)acc[mt][8 + jq][i];
        if (row < N) rhb[o] = (_Float16)(dvr * hv * rr);
      }
    }
  }
  const size_t fo = ((size_t)blockIdx.x * 256 + threadIdx.x) * 32;
  #pragma unroll
  for (int q = 0; q < 4; q++){
    *(f16x8*)(zbf   + fo + 8 * q) = *(f16x8*)&zf[8 * q];
    *(f16x8*)(t1f   + fo + 8 * q) = *(f16x8*)&tf[8 * q];
    *(f16x8*)(zhf_g + fo + 8 * q) = *(f16x8*)&zhf[8 * q];
  }
}

// ---------------------------------------------------------------------------
// MFMA output kernel v3: acc = t1(frag) + Arh @ Bo; ho = zh + (1-z)*tanh(acc).
// No Hh read. Epilogue staged through padded LDS (stride 65) -> coalesced
// float4 o1/o2 writes; XHnext packed coalesced. Wave-synchronous LDS (no
// barrier: early-exited waves make __syncthreads unsafe).
// ---------------------------------------------------------------------------
__global__ __launch_bounds__(256) void outm_k(
    const _Float16* __restrict__ Arh, const _Float16* __restrict__ t1f,
    const _Float16* __restrict__ zbf, const _Float16* __restrict__ zhf_g,
    const float* __restrict__ dinv,
    const _Float16* __restrict__ Bo,
    float* __restrict__ o1, float* __restrict__ o2,
    const float* __restrict__ hNext, __half2* __restrict__ XHnext,
    int doPack, int N)
{
  __shared__ float lds_os[4][16 * 65];
  const int lane = threadIdx.x & 63;
  const int wv   = threadIdx.x >> 6;
  const long nbase = ((long)blockIdx.x * 4 + wv) * 32;
  if (nbase >= N) return;
  const int m  = lane & 15;
  const int kb = lane >> 4;
  const size_t fo = ((size_t)blockIdx.x * 256 + threadIdx.x) * 32;

  _Float16 tf[32];
  #pragma unroll
  for (int q = 0; q < 4; q++)
    *(f16x8*)&tf[8 * q] = *(const f16x8*)(t1f + fo + 8 * q);

  f32x4 acc[2][4];
  #pragma unroll
  for (int mt = 0; mt < 2; mt++)
    #pragma unroll
    for (int jt = 0; jt < 4; jt++)
      #pragma unroll
      for (int i = 0; i < 4; i++)
        acc[mt][jt][i] = (float)tf[mt * 16 + jt * 4 + i];

  #pragma unroll
  for (int ks = 0; ks < 2; ks++){
    f16x8 af0, af1;
    {
      long r0 = nbase + m;           if (r0 >= N) r0 = N - 1;
      long r1 = nbase + 16 + m;      if (r1 >= N) r1 = N - 1;
      af0 = *(const f16x8*)(Arh + (size_t)r0 * 64 + ks * 32 + kb * 8);
      af1 = *(const f16x8*)(Arh + (size_t)r1 * 64 + ks * 32 + kb * 8);
    }
    #pragma unroll
    for (int jt = 0; jt < 4; jt++){
      f16x8 bf = *(const f16x8*)(Bo + ((size_t)(jt * 2 + ks) * 64 + lane) * 8);
      acc[0][jt] = __builtin_amdgcn_mfma_f32_16x16x32_f16(af0, bf, acc[0][jt], 0, 0, 0);
      acc[1][jt] = __builtin_amdgcn_mfma_f32_16x16x32_f16(af1, bf, acc[1][jt], 0, 0, 0);
    }
  }

  _Float16 zf[32], zhf[32];
  #pragma unroll
  for (int q = 0; q < 4; q++){
    *(f16x8*)&zf[8 * q]  = *(const f16x8*)(zbf   + fo + 8 * q);
    *(f16x8*)&zhf[8 * q] = *(const f16x8*)(zhf_g + fo + 8 * q);
  }

  const int rl2 = lane >> 2;          // 0..15
  const int c0  = (lane & 3) * 16;    // 0,16,32,48

  #pragma unroll
  for (int mt = 0; mt < 2; mt++){
    // compute ho into LDS tile (frag positions)
    #pragma unroll
    for (int i = 0; i < 4; i++){
      const int rl = kb * 4 + i;
      #pragma unroll
      for (int jt = 0; jt < 4; jt++){
        const int idx = mt * 16 + jt * 4 + i;
        float e  = __expf(2.0f * acc[mt][jt][i]);
        float ht = 1.0f - 2.0f / (e + 1.0f);
        float z  = (float)zf[idx];
        lds_os[wv][rl * 65 + jt * 16 + m] = (float)zhf[idx] + (1.0f - z) * ht;
      }
    }
    // coalesced writes from LDS (wave-synchronous)
    long grow = nbase + mt * 16 + rl2;
    bool vr = grow < N;
    long gc = vr ? grow : N - 1;
    #pragma unroll
    for (int q = 0; q < 4; q++){
      float4 v = *(float4*)&lds_os[wv][rl2 * 65 + c0 + q * 4];
      if (vr){
        *(float4*)(o1 + gc * 64 + c0 + q * 4) = v;
        *(float4*)(o2 + gc * 64 + c0 + q * 4) = v;
      }
    }
    if (doPack && vr){
      float dvr = dinv[gc];
      #pragma unroll
      for (int q = 0; q < 4; q++){
        float4 hov = *(float4*)&lds_os[wv][rl2 * 65 + c0 + q * 4];
        float4 hnv = *(const float4*)(hNext + gc * 64 + c0 + q * 4);
        __half2 tmp[4];
        tmp[0].x = __float2half_rn(dvr * hov.x); tmp[0].y = __float2half_rn(dvr * hnv.x);
        tmp[1].x = __float2half_rn(dvr * hov.y); tmp[1].y = __float2half_rn(dvr * hnv.y);
        tmp[2].x = __float2half_rn(dvr * hov.z); tmp[2].y = __float2half_rn(dvr * hnv.z);
        tmp[3].x = __float2half_rn(dvr * hov.w); tmp[3].y = __float2half_rn(dvr * hnv.w);
        *(float4*)(XHnext + gc * 64 + c0 + q * 4) = *(float4*)tmp;
      }
    }
  }
}

extern "C" void kernel_launch(void* const* d_in, const int* in_sizes, int n_in,
                              void* d_out, int out_size, void* d_ws, size_t ws_size,
                              hipStream_t stream){
  const float* inp = (const float*)d_in[0];
  const float* h   = (const float*)d_in[1];
  const int*   edg = (const int*)d_in[2];
  const float* Wxz = (const float*)d_in[3];
  const float* Whz = (const float*)d_in[4];
  const float* Wxr = (const float*)d_in[5];
  const float* Whr = (const float*)d_in[6];
  const float* Wxh = (const float*)d_in[7];
  const float* Whh = (const float*)d_in[8];
  const float* bxz = (const float*)d_in[9];
  const float* bhz = (const float*)d_in[10];
  const float* bxr = (const float*)d_in[11];
  const float* bhr = (const float*)d_in[12];
  const float* bxh = (const float*)d_in[13];
  const float* bhh = (const float*)d_in[14];
  float* out = (float*)d_out;

  const int ND = in_sizes[0];
  const int N  = ND / DD;
  const int E  = in_sizes[2] / 2;
  const int L  = in_sizes[1] / ND;

  const int nr  = divup(N, NRG);                 // ranges (196 @ N=100K)
  const int per = divup(E, BB);                  // edges per bin block
  const int cap = (per / nr) * 3 + 64;           // sub-buffer capacity (~3x mean)
  const int mBlocks = divup(N, 128);             // MFMA kernels: 4 waves x 32 nodes

  char* p = (char*)d_ws;
  auto alloc = [&](size_t bytes) -> void* {
    void* r = (void*)p;
    p += ((bytes + 255) / 256) * 256;
    return r;
  };
  auto a256 = [](size_t b) -> size_t { return ((b + 255) / 256) * 256; };

  int*      offsets = (int*)alloc((size_t)(N + 1) * 4);
  int*      locoff  = (int*)alloc((size_t)N * 4);
  int*      rtot    = (int*)alloc(256 * 4);
  int*      rbase   = (int*)alloc(256 * 4);
  float*    dinv    = (float*)alloc((size_t)N * 4);
  int*      cntc    = (int*)alloc((size_t)BB * nr * 4);
  int*      cntr    = (int*)alloc((size_t)BB * nr * 4);
  int*      csr_src = (int*)alloc((size_t)E * 4);
  __half2*  XH      = (__half2*)alloc((size_t)ND * 4);     // dinv-scaled (x,h)
  _Float16* Bg      = (_Float16*)alloc((size_t)L * 24576 * 2);
  _Float16* Bo      = (_Float16*)alloc((size_t)L * 4096 * 2);
  float*    biasg   = (float*)alloc((size_t)L * 192 * 4);

  // overlay: {bufc|bufr} (CSR build) reuses {AXAH|Arh|rhb|zbf|t1f|zhf} (layers)
  size_t bufc_b  = a256((size_t)BB * nr * cap * 4);
  size_t bufr_b  = a256((size_t)BB * nr * cap * 2);
  size_t axah_b  = a256((size_t)N * 128 * 2);
  size_t nd2_b   = a256((size_t)ND * 2);
  size_t frag_b  = a256((size_t)mBlocks * 128 * 64 * 2);   // padded-N frag buf
  size_t ov_b    = axah_b + 2 * nd2_b + 3 * frag_b;
  if (bufc_b + bufr_b > ov_b) ov_b = bufc_b + bufr_b;
  char* ov = (char*)alloc(ov_b);
  unsigned int*   bufc = (unsigned int*)ov;
  unsigned short* bufr = (unsigned short*)(ov + bufc_b);
  _Float16* AXAH = (_Float16*)ov;
  _Float16* Arh  = (_Float16*)(ov + axah_b);
  _Float16* rhb  = (_Float16*)(ov + axah_b + nd2_b);
  _Float16* zbf  = (_Float16*)(ov + axah_b + 2 * nd2_b);
  _Float16* t1f  = (_Float16*)(ov + axah_b + 2 * nd2_b + frag_b);
  _Float16* zhf  = (_Float16*)(ov + axah_b + 2 * nd2_b + 2 * frag_b);

  // --- CSR build: bin -> hist+local-scan -> range scan -> scatter ---
  bin_k<<<BB, 256, 2 * nr * 4, stream>>>(edg, E, per, nr, cap, bufc, bufr, cntc, cntr);
  cnt2b_k<<<nr, 256, 0, stream>>>(bufc, bufr, cntc, cntr, BB, nr, cap,
                                  locoff, rtot, dinv, N);
  rscan_k<<<1, 256, 0, stream>>>(rtot, rbase, offsets, nr, E, N);
  scat_k<<<nr, 256, 0, stream>>>(bufc, cntc, BB, nr, cap, locoff, rbase,
                                 offsets, csr_src, N);

  pack0_k<<<divup(ND, 256), 256, 0, stream>>>(inp, h, dinv, XH, ND);
  {
    const int PER = 24576 + 4096 + 192;
    packb_k<<<divup(L * PER, 256), 256, 0, stream>>>(
        Wxz, Whz, Wxr, Whr, Wxh, Whh,
        bxz, bhz, bxr, bhr, bxh, bhh, Bg, Bo, biasg, L);
  }

  const int aggBlocks = divup(N, 4);     // 4 waves (nodes) per 256-thread block

  for (int l = 0; l < L; l++){
    const float* Hh = h + (size_t)l * ND;
    agg2_k<<<aggBlocks, 256, 0, stream>>>(XH, offsets, csr_src, dinv, AXAH, N);
    gatem_k<<<mBlocks, 256, 0, stream>>>(AXAH, Hh, dinv,
        Bg + (size_t)l * 24576, biasg + (size_t)l * 192, zbf, zhf, rhb, t1f, N);
    agg1_k<<<aggBlocks, 256, 0, stream>>>(rhb, offsets, csr_src, dinv, Arh, N);
    const int doPack = (l + 1 < L);
    outm_k<<<mBlocks, 256, 0, stream>>>(Arh, t1f, zbf, zhf, dinv,
        Bo + (size_t)l * 4096,
        out + (size_t)l * ND, out + (size_t)L * ND + (size_t)l * ND,
        h + (size_t)(l + 1 < L ? l + 1 : l) * ND, XH, doPack, N);
  }
}

// Round 14
// 536.533 us; speedup vs baseline: 1.0334x; 1.0334x over previous
//
#include <hip/hip_runtime.h>
#include <hip/hip_fp16.h>
#include <math.h>
#include <stdint.h>

#define DD 64
#define NRG 512        // nodes per range (9 bits)
#define BB  128        // binning blocks

using f16x8 = __attribute__((ext_vector_type(8))) _Float16;
using f32x4 = __attribute__((ext_vector_type(4))) float;

static inline int divup(int a, int b){ return (a + b - 1) / b; }

// ---------------------------------------------------------------------------
// CSR build, zero global atomics (R9: memory-side RMW ~150ns/op on hot words).
// ---------------------------------------------------------------------------
__global__ __launch_bounds__(256) void bin_k(
    const int* __restrict__ edg, int E, int per, int nr, int cap,
    unsigned int* __restrict__ bufc, unsigned short* __restrict__ bufr,
    int* __restrict__ cntc, int* __restrict__ cntr)
{
  extern __shared__ int cur[];            // [nr] col cursors | [nr] row cursors
  int* curc = cur;
  int* curr = cur + nr;
  const int b = blockIdx.x, t = threadIdx.x;
  for (int i = t; i < 2 * nr; i += 256) cur[i] = 0;
  __syncthreads();
  const int e0 = b * per;
  const int e1 = (e0 + per < E) ? e0 + per : E;
  unsigned int* mybufc = bufc + (size_t)b * nr * cap;
  unsigned short* mybufr = bufr + (size_t)b * nr * cap;
  for (int e = e0 + t; e < e1; e += 256){
    int r = edg[e];
    int c = edg[E + e];
    int rg = c >> 9;
    int p = atomicAdd(&curc[rg], 1);      // LDS atomic
    if (p < cap) mybufc[rg * cap + p] = ((unsigned int)r << 9) | (unsigned int)(c & 511);
    int rr = r >> 9;
    int q = atomicAdd(&curr[rr], 1);      // LDS atomic
    if (q < cap) mybufr[rr * cap + q] = (unsigned short)(r & 511);
  }
  __syncthreads();
  for (int i = t; i < nr; i += 256){
    int vc = curc[i]; cntc[b * nr + i] = vc < cap ? vc : cap;
    int vr = curr[i]; cntr[b * nr + i] = vr < cap ? vr : cap;
  }
}

// --- per-range histograms + in-LDS exclusive scan -> locoff, rtot, dinv ---
__global__ __launch_bounds__(256) void cnt2b_k(
    const unsigned int* __restrict__ bufc, const unsigned short* __restrict__ bufr,
    const int* __restrict__ cntc, const int* __restrict__ cntr,
    int nb, int nr, int cap,
    int* __restrict__ locoff, int* __restrict__ rtot, float* __restrict__ dinv, int N)
{
  __shared__ int lhc[NRG];
  __shared__ int lhr[NRG];
  __shared__ int lcc[BB];
  __shared__ int lcr[BB];
  __shared__ int ps[256];
  const int rg = blockIdx.x, t = threadIdx.x;
  for (int i = t; i < NRG; i += 256){ lhc[i] = 0; lhr[i] = 0; }
  for (int i = t; i < nb; i += 256){ lcc[i] = cntc[i * nr + rg]; lcr[i] = cntr[i * nr + rg]; }
  __syncthreads();
  const int wv = t >> 6, lane = t & 63;
  for (int b = wv; b < nb; b += 4){
    const unsigned int* buf = bufc + ((size_t)b * nr + rg) * cap;
    int cnt = lcc[b];
    for (int i = lane; i < cnt; i += 64) atomicAdd(&lhc[buf[i] & 511], 1);
    const unsigned short* bufR = bufr + ((size_t)b * nr + rg) * cap;
    int cntR = lcr[b];
    for (int i = lane; i < cntR; i += 64) atomicAdd(&lhr[bufR[i]], 1);
  }
  __syncthreads();
  for (int i = t; i < NRG; i += 256){
    int node = rg * NRG + i;
    if (node < N) dinv[node] = rsqrtf((float)lhr[i] + 2.0f);
  }
  int v0 = lhc[2 * t], v1 = lhc[2 * t + 1];
  int s = v0 + v1;
  ps[t] = s; __syncthreads();
  for (int off = 1; off < 256; off <<= 1){
    int x = (t >= off) ? ps[t - off] : 0;
    __syncthreads();
    ps[t] += x;
    __syncthreads();
  }
  int excl = ps[t] - s;
  int n0 = rg * NRG + 2 * t;
  if (n0 < N)     locoff[n0]     = excl;
  if (n0 + 1 < N) locoff[n0 + 1] = excl + v0;
  if (t == 255) rtot[rg] = ps[255];
}

__global__ void rscan_k(const int* __restrict__ rtot, int* __restrict__ rbase,
                        int* __restrict__ offsets, int nr, int E, int N){
  __shared__ int sh[256];
  int t = threadIdx.x;
  int v = (t < nr) ? rtot[t] : 0;
  sh[t] = v; __syncthreads();
  for (int off = 1; off < 256; off <<= 1){
    int x = (t >= off) ? sh[t - off] : 0;
    __syncthreads();
    sh[t] += x;
    __syncthreads();
  }
  if (t < nr) rbase[t] = sh[t] - v;
  if (t == 0) offsets[N] = E;
}

// --- per-range CSR scatter: LDS cursors = rbase+locoff; writes offsets[] ---
__global__ __launch_bounds__(256) void scat_k(
    const unsigned int* __restrict__ bufc, const int* __restrict__ cntc,
    int nb, int nr, int cap, const int* __restrict__ locoff,
    const int* __restrict__ rbase,
    int* __restrict__ offsets, int* __restrict__ csr_src, int N)
{
  __shared__ int loff[NRG];
  __shared__ int lcc[BB];
  const int rg = blockIdx.x, t = threadIdx.x;
  const int base = rbase[rg];
  for (int i = t; i < NRG; i += 256){
    int node = rg * NRG + i;
    if (node < N){
      int o = base + locoff[node];
      loff[i] = o;
      offsets[node] = o;
    } else loff[i] = 0;
  }
  for (int i = t; i < nb; i += 256) lcc[i] = cntc[i * nr + rg];
  __syncthreads();
  const int wv = t >> 6, lane = t & 63;
  for (int b = wv; b < nb; b += 4){
    const unsigned int* buf = bufc + ((size_t)b * nr + rg) * cap;
    int cnt = lcc[b];
    for (int i = lane; i < cnt; i += 64){
      unsigned int v = buf[i];
      int p = atomicAdd(&loff[v & 511], 1);   // LDS atomic
      csr_src[p] = (int)(v >> 9);
    }
  }
}

// --- pack layer-0: XH[n][j] = dinv[n]*(x, h) fp16 ---
__global__ void pack0_k(const float* __restrict__ X, const float* __restrict__ H,
                        const float* __restrict__ dinv, __half2* __restrict__ XH, int total){
  int i = blockIdx.x * 256 + threadIdx.x;
  if (i < total){
    float dv = dinv[i >> 6];
    __half2 v;
    v.x = __float2half_rn(dv * X[i]);
    v.y = __float2half_rn(dv * H[i]);
    XH[i] = v;
  }
}

// --- pack weights into MFMA B-fragment order + fused biases (see R8) ---
__global__ void packb_k(const float* __restrict__ Wxz, const float* __restrict__ Whz,
                        const float* __restrict__ Wxr, const float* __restrict__ Whr,
                        const float* __restrict__ Wxh, const float* __restrict__ Whh,
                        const float* __restrict__ bxz, const float* __restrict__ bhz,
                        const float* __restrict__ bxr, const float* __restrict__ bhr,
                        const float* __restrict__ bxh, const float* __restrict__ bhh,
                        _Float16* __restrict__ Bg, _Float16* __restrict__ Bo,
                        float* __restrict__ biasg, int L){
  const int PER = 24576 + 4096 + 192;
  int tid = blockIdx.x * 256 + threadIdx.x;
  if (tid >= L * PER) return;
  int l = tid / PER, r = tid % PER;
  if (r < 24576){
    int q = r;
    int s = q & 7, lane = (q >> 3) & 63, ks = (q >> 9) & 3, jt = q >> 11;
    int k = ks * 32 + (lane >> 4) * 8 + s;
    int b = jt >> 2;
    int j = (jt & 3) * 16 + (lane & 15);
    const float* Wx = (b == 0) ? Wxz : (b == 1) ? Wxr : Wxh;
    const float* Wh = (b == 0) ? Whz : Whr;
    float v;
    if (k < 64) v = Wx[(size_t)l * 4096 + k * 64 + j];
    else        v = (b == 2) ? 0.0f : Wh[(size_t)l * 4096 + (k - 64) * 64 + j];
    Bg[(size_t)l * 24576 + q] = (_Float16)v;
  } else if (r < 24576 + 4096){
    int q = r - 24576;
    int s = q & 7, lane = (q >> 3) & 63, ks = (q >> 9) & 1, jt = q >> 10;
    int k = ks * 32 + (lane >> 4) * 8 + s;
    int j = jt * 16 + (lane & 15);
    Bo[(size_t)l * 4096 + q] = (_Float16)Whh[(size_t)l * 4096 + k * 64 + j];
  } else {
    int j = r - (24576 + 4096);
    int b = j >> 6, jj = j & 63;
    float v = (b == 0) ? bxz[l * 64 + jj] + bhz[l * 64 + jj]
            : (b == 1) ? bxr[l * 64 + jj] + bhr[l * 64 + jj]
                       : bxh[l * 64 + jj] + bhh[l * 64 + jj];
    biasg[l * 192 + j] = v;
  }
}

// --- aggregation of pre-scaled (x,h) rows, unroll 8 ---
__global__ void agg2_k(const __half2* __restrict__ XH,
                       const int* __restrict__ offsets, const int* __restrict__ src,
                       const float* __restrict__ dinv,
                       _Float16* __restrict__ AXAH, int N){
  int wid = (blockIdx.x * blockDim.x + threadIdx.x) >> 6;
  int lane = threadIdx.x & 63;
  if (wid >= N) return;
  float dv = dinv[wid];
  size_t me = (size_t)wid * DD + lane;
  float2 sf = __half22float2(XH[me]);
  float ax[8], ah[8];
  #pragma unroll
  for (int j = 0; j < 8; j++){ ax[j] = 0.0f; ah[j] = 0.0f; }
  int s0 = offsets[wid], s1 = offsets[wid + 1];
  int e = s0;
  for (; e + 8 <= s1; e += 8){
    int sn[8];
    float2 f[8];
    #pragma unroll
    for (int j = 0; j < 8; j++) sn[j] = src[e + j];
    #pragma unroll
    for (int j = 0; j < 8; j++) f[j] = __half22float2(XH[(size_t)sn[j] * DD + lane]);
    #pragma unroll
    for (int j = 0; j < 8; j++){
      ax[j] += f[j].x;
      ah[j] += f[j].y;
    }
  }
  for (; e < s1; ++e){
    float2 fa = __half22float2(XH[(size_t)src[e] * DD + lane]);
    ax[0] += fa.x;
    ah[0] += fa.y;
  }
  float axs = ((ax[0] + ax[1]) + (ax[2] + ax[3])) + ((ax[4] + ax[5]) + (ax[6] + ax[7]));
  float ahs = ((ah[0] + ah[1]) + (ah[2] + ah[3])) + ((ah[4] + ah[5]) + (ah[6] + ah[7]));
  size_t o = (size_t)wid * 128 + lane;
  AXAH[o]      = (_Float16)(dv * (axs + 2.0f * sf.x));
  AXAH[o + 64] = (_Float16)(dv * (ahs + 2.0f * sf.y));
}

// --- aggregation of pre-scaled r*h rows, unroll 8 ---
__global__ void agg1_k(const _Float16* __restrict__ RH,
                       const int* __restrict__ offsets, const int* __restrict__ src,
                       const float* __restrict__ dinv,
                       _Float16* __restrict__ Arh, int N){
  int wid = (blockIdx.x * blockDim.x + threadIdx.x) >> 6;
  int lane = threadIdx.x & 63;
  if (wid >= N) return;
  float dv = dinv[wid];
  size_t me = (size_t)wid * DD + lane;
  float selfv = (float)RH[me];
  float ax[8];
  #pragma unroll
  for (int j = 0; j < 8; j++) ax[j] = 0.0f;
  int s0 = offsets[wid], s1 = offsets[wid + 1];
  int e = s0;
  for (; e + 8 <= s1; e += 8){
    int sn[8];
    float f[8];
    #pragma unroll
    for (int j = 0; j < 8; j++) sn[j] = src[e + j];
    #pragma unroll
    for (int j = 0; j < 8; j++) f[j] = (float)RH[(size_t)sn[j] * DD + lane];
    #pragma unroll
    for (int j = 0; j < 8; j++) ax[j] += f[j];
  }
  for (; e < s1; ++e){
    ax[0] += (float)RH[(size_t)src[e] * DD + lane];
  }
  float axs = ((ax[0] + ax[1]) + (ax[2] + ax[3])) + ((ax[4] + ax[5]) + (ax[6] + ax[7]));
  Arh[me] = (_Float16)(dv * (axs + 2.0f * selfv));
}

// ---------------------------------------------------------------------------
// MFMA gate kernel v4: C(N x 192) = AXAH @ Bg + bias.
// zb, t1, zh(=z*h) stored in WAVE-INTERLEAVED fragment layout:
//   elem(gw, q, lane, e) at gw*2048 + q*512 + lane*8 + e
// -> each f16x8 store is 64 lanes x 16B = 1KB fully coalesced (R13 bug:
// gtid*32 gave 64B-strided lanes, 25% line utilization).
// ---------------------------------------------------------------------------
__global__ __launch_bounds__(256) void gatem_k(
    const _Float16* __restrict__ AXAH, const float* __restrict__ Hh,
    const float* __restrict__ dinv,
    const _Float16* __restrict__ Bg, const float* __restrict__ biasg,
    _Float16* __restrict__ zbf, _Float16* __restrict__ zhf_g,
    _Float16* __restrict__ rhb, _Float16* __restrict__ t1f, int N)
{
  const int lane = threadIdx.x & 63;
  const int wv   = threadIdx.x >> 6;
  const long nbase = ((long)blockIdx.x * 4 + wv) * 32;
  if (nbase >= N) return;
  const int m  = lane & 15;
  const int kb = lane >> 4;

  f32x4 acc[2][12];
  #pragma unroll
  for (int jt = 0; jt < 12; jt++){
    float bv = biasg[jt * 16 + m];
    f32x4 b4 = {bv, bv, bv, bv};
    acc[0][jt] = b4;
    acc[1][jt] = b4;
  }

  #pragma unroll 1
  for (int ks = 0; ks < 4; ks++){
    f16x8 af0, af1;
    {
      long r0 = nbase + m;           if (r0 >= N) r0 = N - 1;
      long r1 = nbase + 16 + m;      if (r1 >= N) r1 = N - 1;
      af0 = *(const f16x8*)(AXAH + (size_t)r0 * 128 + ks * 32 + kb * 8);
      af1 = *(const f16x8*)(AXAH + (size_t)r1 * 128 + ks * 32 + kb * 8);
    }
    #pragma unroll
    for (int jt = 0; jt < 12; jt++){
      f16x8 bf = *(const f16x8*)(Bg + ((size_t)(jt * 4 + ks) * 64 + lane) * 8);
      acc[0][jt] = __builtin_amdgcn_mfma_f32_16x16x32_f16(af0, bf, acc[0][jt], 0, 0, 0);
      acc[1][jt] = __builtin_amdgcn_mfma_f32_16x16x32_f16(af1, bf, acc[1][jt], 0, 0, 0);
    }
  }

  _Float16 zf[32], tf[32], zhf[32];
  #pragma unroll
  for (int mt = 0; mt < 2; mt++){
    #pragma unroll
    for (int i = 0; i < 4; i++){
      long row = nbase + mt * 16 + kb * 4 + i;
      long rc = row < N ? row : N - 1;
      float dvr = dinv[rc];
      #pragma unroll
      for (int jq = 0; jq < 4; jq++){
        int j = jq * 16 + m;
        size_t o = (size_t)rc * 64 + j;
        float hv = Hh[o];
        float z  = 1.0f / (1.0f + __expf(-acc[mt][jq][i]));
        float rr = 1.0f / (1.0f + __expf(-acc[mt][4 + jq][i]));
        const int idx = mt * 16 + jq * 4 + i;
        zf[idx]  = (_Float16)z;
        zhf[idx] = (_Float16)(z * hv);
        tf[idx]  = (_Float16)acc[mt][8 + jq][i];
        if (row < N) rhb[o] = (_Float16)(dvr * hv * rr);
      }
    }
  }
  const size_t fo = ((size_t)(blockIdx.x * 4 + wv)) * 2048 + (size_t)lane * 8;
  #pragma unroll
  for (int q = 0; q < 4; q++){
    *(f16x8*)(zbf   + fo + q * 512) = *(f16x8*)&zf[8 * q];
    *(f16x8*)(t1f   + fo + q * 512) = *(f16x8*)&tf[8 * q];
    *(f16x8*)(zhf_g + fo + q * 512) = *(f16x8*)&zhf[8 * q];
  }
}

// ---------------------------------------------------------------------------
// MFMA output kernel v4: acc = t1(frag) + Arh @ Bo; ho = zh + (1-z)*tanh(acc).
// Frag loads wave-interleaved (coalesced). Epilogue via padded LDS (stride 65)
// -> coalesced float4 o1/o2 writes; XHnext packed coalesced. Wave-synchronous
// LDS (no barrier: early-exited waves make __syncthreads unsafe).
// ---------------------------------------------------------------------------
__global__ __launch_bounds__(256) void outm_k(
    const _Float16* __restrict__ Arh, const _Float16* __restrict__ t1f,
    const _Float16* __restrict__ zbf, const _Float16* __restrict__ zhf_g,
    const float* __restrict__ dinv,
    const _Float16* __restrict__ Bo,
    float* __restrict__ o1, float* __restrict__ o2,
    const float* __restrict__ hNext, __half2* __restrict__ XHnext,
    int doPack, int N)
{
  __shared__ float lds_os[4][16 * 65];
  const int lane = threadIdx.x & 63;
  const int wv   = threadIdx.x >> 6;
  const long nbase = ((long)blockIdx.x * 4 + wv) * 32;
  if (nbase >= N) return;
  const int m  = lane & 15;
  const int kb = lane >> 4;
  const size_t fo = ((size_t)(blockIdx.x * 4 + wv)) * 2048 + (size_t)lane * 8;

  _Float16 tf[32];
  #pragma unroll
  for (int q = 0; q < 4; q++)
    *(f16x8*)&tf[8 * q] = *(const f16x8*)(t1f + fo + q * 512);

  f32x4 acc[2][4];
  #pragma unroll
  for (int mt = 0; mt < 2; mt++)
    #pragma unroll
    for (int jt = 0; jt < 4; jt++)
      #pragma unroll
      for (int i = 0; i < 4; i++)
        acc[mt][jt][i] = (float)tf[mt * 16 + jt * 4 + i];

  #pragma unroll
  for (int ks = 0; ks < 2; ks++){
    f16x8 af0, af1;
    {
      long r0 = nbase + m;           if (r0 >= N) r0 = N - 1;
      long r1 = nbase + 16 + m;      if (r1 >= N) r1 = N - 1;
      af0 = *(const f16x8*)(Arh + (size_t)r0 * 64 + ks * 32 + kb * 8);
      af1 = *(const f16x8*)(Arh + (size_t)r1 * 64 + ks * 32 + kb * 8);
    }
    #pragma unroll
    for (int jt = 0; jt < 4; jt++){
      f16x8 bf = *(const f16x8*)(Bo + ((size_t)(jt * 2 + ks) * 64 + lane) * 8);
      acc[0][jt] = __builtin_amdgcn_mfma_f32_16x16x32_f16(af0, bf, acc[0][jt], 0, 0, 0);
      acc[1][jt] = __builtin_amdgcn_mfma_f32_16x16x32_f16(af1, bf, acc[1][jt], 0, 0, 0);
    }
  }

  _Float16 zf[32], zhf[32];
  #pragma unroll
  for (int q = 0; q < 4; q++){
    *(f16x8*)&zf[8 * q]  = *(const f16x8*)(zbf   + fo + q * 512);
    *(f16x8*)&zhf[8 * q] = *(const f16x8*)(zhf_g + fo + q * 512);
  }

  const int rl2 = lane >> 2;          // 0..15
  const int c0  = (lane & 3) * 16;    // 0,16,32,48

  #pragma unroll
  for (int mt = 0; mt < 2; mt++){
    // compute ho into LDS tile (frag positions)
    #pragma unroll
    for (int i = 0; i < 4; i++){
      const int rl = kb * 4 + i;
      #pragma unroll
      for (int jt = 0; jt < 4; jt++){
        const int idx = mt * 16 + jt * 4 + i;
        float e  = __expf(2.0f * acc[mt][jt][i]);
        float ht = 1.0f - 2.0f / (e + 1.0f);
        float z  = (float)zf[idx];
        lds_os[wv][rl * 65 + jt * 16 + m] = (float)zhf[idx] + (1.0f - z) * ht;
      }
    }
    // coalesced writes from LDS (wave-synchronous)
    long grow = nbase + mt * 16 + rl2;
    bool vr = grow < N;
    long gc = vr ? grow : N - 1;
    #pragma unroll
    for (int q = 0; q < 4; q++){
      float4 v = *(float4*)&lds_os[wv][rl2 * 65 + c0 + q * 4];
      if (vr){
        *(float4*)(o1 + gc * 64 + c0 + q * 4) = v;
        *(float4*)(o2 + gc * 64 + c0 + q * 4) = v;
      }
    }
    if (doPack && vr){
      float dvr = dinv[gc];
      #pragma unroll
      for (int q = 0; q < 4; q++){
        float4 hov = *(float4*)&lds_os[wv][rl2 * 65 + c0 + q * 4];
        float4 hnv = *(const float4*)(hNext + gc * 64 + c0 + q * 4);
        __half2 tmp[4];
        tmp[0].x = __float2half_rn(dvr * hov.x); tmp[0].y = __float2half_rn(dvr * hnv.x);
        tmp[1].x = __float2half_rn(dvr * hov.y); tmp[1].y = __float2half_rn(dvr * hnv.y);
        tmp[2].x = __float2half_rn(dvr * hov.z); tmp[2].y = __float2half_rn(dvr * hnv.z);
        tmp[3].x = __float2half_rn(dvr * hov.w); tmp[3].y = __float2half_rn(dvr * hnv.w);
        *(float4*)(XHnext + gc * 64 + c0 + q * 4) = *(float4*)tmp;
      }
    }
  }
}

extern "C" void kernel_launch(void* const* d_in, const int* in_sizes, int n_in,
                              void* d_out, int out_size, void* d_ws, size_t ws_size,
                              hipStream_t stream){
  const float* inp = (const float*)d_in[0];
  const float* h   = (const float*)d_in[1];
  const int*   edg = (const int*)d_in[2];
  const float* Wxz = (const float*)d_in[3];
  const float* Whz = (const float*)d_in[4];
  const float* Wxr = (const float*)d_in[5];
  const float* Whr = (const float*)d_in[6];
  const float* Wxh = (const float*)d_in[7];
  const float* Whh = (const float*)d_in[8];
  const float* bxz = (const float*)d_in[9];
  const float* bhz = (const float*)d_in[10];
  const float* bxr = (const float*)d_in[11];
  const float* bhr = (const float*)d_in[12];
  const float* bxh = (const float*)d_in[13];
  const float* bhh = (const float*)d_in[14];
  float* out = (float*)d_out;

  const int ND = in_sizes[0];
  const int N  = ND / DD;
  const int E  = in_sizes[2] / 2;
  const int L  = in_sizes[1] / ND;

  const int nr  = divup(N, NRG);                 // ranges (196 @ N=100K)
  const int per = divup(E, BB);                  // edges per bin block
  const int cap = (per / nr) * 3 + 64;           // sub-buffer capacity (~3x mean)
  const int mBlocks = divup(N, 128);             // MFMA kernels: 4 waves x 32 nodes

  char* p = (char*)d_ws;
  auto alloc = [&](size_t bytes) -> void* {
    void* r = (void*)p;
    p += ((bytes + 255) / 256) * 256;
    return r;
  };
  auto a256 = [](size_t b) -> size_t { return ((b + 255) / 256) * 256; };

  int*      offsets = (int*)alloc((size_t)(N + 1) * 4);
  int*      locoff  = (int*)alloc((size_t)N * 4);
  int*      rtot    = (int*)alloc(256 * 4);
  int*      rbase   = (int*)alloc(256 * 4);
  float*    dinv    = (float*)alloc((size_t)N * 4);
  int*      cntc    = (int*)alloc((size_t)BB * nr * 4);
  int*      cntr    = (int*)alloc((size_t)BB * nr * 4);
  int*      csr_src = (int*)alloc((size_t)E * 4);
  __half2*  XH      = (__half2*)alloc((size_t)ND * 4);     // dinv-scaled (x,h)
  _Float16* Bg      = (_Float16*)alloc((size_t)L * 24576 * 2);
  _Float16* Bo      = (_Float16*)alloc((size_t)L * 4096 * 2);
  float*    biasg   = (float*)alloc((size_t)L * 192 * 4);

  // overlay: {bufc|bufr} (CSR build) reuses {AXAH|Arh|rhb|zbf|t1f|zhf} (layers)
  size_t bufc_b  = a256((size_t)BB * nr * cap * 4);
  size_t bufr_b  = a256((size_t)BB * nr * cap * 2);
  size_t axah_b  = a256((size_t)N * 128 * 2);
  size_t nd2_b   = a256((size_t)ND * 2);
  size_t frag_b  = a256((size_t)mBlocks * 4 * 2048 * 2);   // wave-interleaved frag buf
  size_t ov_b    = axah_b + 2 * nd2_b + 3 * frag_b;
  if (bufc_b + bufr_b > ov_b) ov_b = bufc_b + bufr_b;
  char* ov = (char*)alloc(ov_b);
  unsigned int*   bufc = (unsigned int*)ov;
  unsigned short* bufr = (unsigned short*)(ov + bufc_b);
  _Float16* AXAH = (_Float16*)ov;
  _Float16* Arh  = (_Float16*)(ov + axah_b);
  _Float16* rhb  = (_Float16*)(ov + axah_b + nd2_b);
  _Float16* zbf  = (_Float16*)(ov + axah_b + 2 * nd2_b);
  _Float16* t1f  = (_Float16*)(ov + axah_b + 2 * nd2_b + frag_b);
  _Float16* zhf  = (_Float16*)(ov + axah_b + 2 * nd2_b + 2 * frag_b);

  // --- CSR build: bin -> hist+local-scan -> range scan -> scatter ---
  bin_k<<<BB, 256, 2 * nr * 4, stream>>>(edg, E, per, nr, cap, bufc, bufr, cntc, cntr);
  cnt2b_k<<<nr, 256, 0, stream>>>(bufc, bufr, cntc, cntr, BB, nr, cap,
                                  locoff, rtot, dinv, N);
  rscan_k<<<1, 256, 0, stream>>>(rtot, rbase, offsets, nr, E, N);
  scat_k<<<nr, 256, 0, stream>>>(bufc, cntc, BB, nr, cap, locoff, rbase,
                                 offsets, csr_src, N);

  pack0_k<<<divup(ND, 256), 256, 0, stream>>>(inp, h, dinv, XH, ND);
  {
    const int PER = 24576 + 4096 + 192;
    packb_k<<<divup(L * PER, 256), 256, 0, stream>>>(
        Wxz, Whz, Wxr, Whr, Wxh, Whh,
        bxz, bhz, bxr, bhr, bxh, bhh, Bg, Bo, biasg, L);
  }

  const int aggBlocks = divup(N, 4);     // 4 waves (nodes) per 256-thread block

  for (int l = 0; l < L; l++){
    const float* Hh = h + (size_t)l * ND;
    agg2_k<<<aggBlocks, 256, 0, stream>>>(XH, offsets, csr_src, dinv, AXAH, N);
    gatem_k<<<mBlocks, 256, 0, stream>>>(AXAH, Hh, dinv,
        Bg + (size_t)l * 24576, biasg + (size_t)l * 192, zbf, zhf, rhb, t1f, N);
    agg1_k<<<aggBlocks, 256, 0, stream>>>(rhb, offsets, csr_src, dinv, Arh, N);
    const int doPack = (l + 1 < L);
    outm_k<<<mBlocks, 256, 0, stream>>>(Arh, t1f, zbf, zhf, dinv,
        Bo + (size_t)l * 4096,
        out + (size_t)l * ND, out + (size_t)L * ND + (size_t)l * ND,
        h + (size_t)(l + 1 < L ? l + 1 : l) * ND, XH, doPack, N);
  }
}

// Round 15
// 527.953 us; speedup vs baseline: 1.0502x; 1.0163x over previous
//
#include <hip/hip_runtime.h>
#include <hip/hip_fp16.h>
#include <math.h>
#include <stdint.h>

#define DD 64
#define NRG 512        // nodes per range (9 bits)
#define BB  128        // binning blocks

using f16x8 = __attribute__((ext_vector_type(8))) _Float16;
using f32x4 = __attribute__((ext_vector_type(4))) float;

static inline int divup(int a, int b){ return (a + b - 1) / b; }

// ---------------------------------------------------------------------------
// CSR build, zero global atomics (R9: memory-side RMW ~150ns/op on hot words).
// ---------------------------------------------------------------------------
__global__ __launch_bounds__(256) void bin_k(
    const int* __restrict__ edg, int E, int per, int nr, int cap,
    unsigned int* __restrict__ bufc, unsigned short* __restrict__ bufr,
    int* __restrict__ cntc, int* __restrict__ cntr)
{
  extern __shared__ int cur[];            // [nr] col cursors | [nr] row cursors
  int* curc = cur;
  int* curr = cur + nr;
  const int b = blockIdx.x, t = threadIdx.x;
  for (int i = t; i < 2 * nr; i += 256) cur[i] = 0;
  __syncthreads();
  const int e0 = b * per;
  const int e1 = (e0 + per < E) ? e0 + per : E;
  unsigned int* mybufc = bufc + (size_t)b * nr * cap;
  unsigned short* mybufr = bufr + (size_t)b * nr * cap;
  for (int e = e0 + t; e < e1; e += 256){
    int r = edg[e];
    int c = edg[E + e];
    int rg = c >> 9;
    int p = atomicAdd(&curc[rg], 1);      // LDS atomic
    if (p < cap) mybufc[rg * cap + p] = ((unsigned int)r << 9) | (unsigned int)(c & 511);
    int rr = r >> 9;
    int q = atomicAdd(&curr[rr], 1);      // LDS atomic
    if (q < cap) mybufr[rr * cap + q] = (unsigned short)(r & 511);
  }
  __syncthreads();
  for (int i = t; i < nr; i += 256){
    int vc = curc[i]; cntc[b * nr + i] = vc < cap ? vc : cap;
    int vr = curr[i]; cntr[b * nr + i] = vr < cap ? vr : cap;
  }
}

// --- per-range histograms + in-LDS exclusive scan -> locoff, rtot, dinv, rdinv ---
__global__ __launch_bounds__(256) void cnt2b_k(
    const unsigned int* __restrict__ bufc, const unsigned short* __restrict__ bufr,
    const int* __restrict__ cntc, const int* __restrict__ cntr,
    int nb, int nr, int cap,
    int* __restrict__ locoff, int* __restrict__ rtot,
    float* __restrict__ dinv, float* __restrict__ rdinv, int N)
{
  __shared__ int lhc[NRG];
  __shared__ int lhr[NRG];
  __shared__ int lcc[BB];
  __shared__ int lcr[BB];
  __shared__ int ps[256];
  const int rg = blockIdx.x, t = threadIdx.x;
  for (int i = t; i < NRG; i += 256){ lhc[i] = 0; lhr[i] = 0; }
  for (int i = t; i < nb; i += 256){ lcc[i] = cntc[i * nr + rg]; lcr[i] = cntr[i * nr + rg]; }
  __syncthreads();
  const int wv = t >> 6, lane = t & 63;
  for (int b = wv; b < nb; b += 4){
    const unsigned int* buf = bufc + ((size_t)b * nr + rg) * cap;
    int cnt = lcc[b];
    for (int i = lane; i < cnt; i += 64) atomicAdd(&lhc[buf[i] & 511], 1);
    const unsigned short* bufR = bufr + ((size_t)b * nr + rg) * cap;
    int cntR = lcr[b];
    for (int i = lane; i < cntR; i += 64) atomicAdd(&lhr[bufR[i]], 1);
  }
  __syncthreads();
  for (int i = t; i < NRG; i += 256){
    int node = rg * NRG + i;
    if (node < N){
      float d = (float)lhr[i] + 2.0f;
      dinv[node]  = rsqrtf(d);
      rdinv[node] = sqrtf(d);
    }
  }
  int v0 = lhc[2 * t], v1 = lhc[2 * t + 1];
  int s = v0 + v1;
  ps[t] = s; __syncthreads();
  for (int off = 1; off < 256; off <<= 1){
    int x = (t >= off) ? ps[t - off] : 0;
    __syncthreads();
    ps[t] += x;
    __syncthreads();
  }
  int excl = ps[t] - s;
  int n0 = rg * NRG + 2 * t;
  if (n0 < N)     locoff[n0]     = excl;
  if (n0 + 1 < N) locoff[n0 + 1] = excl + v0;
  if (t == 255) rtot[rg] = ps[255];
}

__global__ void rscan_k(const int* __restrict__ rtot, int* __restrict__ rbase,
                        int* __restrict__ offsets, int nr, int E, int N){
  __shared__ int sh[256];
  int t = threadIdx.x;
  int v = (t < nr) ? rtot[t] : 0;
  sh[t] = v; __syncthreads();
  for (int off = 1; off < 256; off <<= 1){
    int x = (t >= off) ? sh[t - off] : 0;
    __syncthreads();
    sh[t] += x;
    __syncthreads();
  }
  if (t < nr) rbase[t] = sh[t] - v;
  if (t == 0) offsets[N] = E;
}

// --- per-range CSR scatter: LDS cursors = rbase+locoff; writes offsets[] ---
__global__ __launch_bounds__(256) void scat_k(
    const unsigned int* __restrict__ bufc, const int* __restrict__ cntc,
    int nb, int nr, int cap, const int* __restrict__ locoff,
    const int* __restrict__ rbase,
    int* __restrict__ offsets, int* __restrict__ csr_src, int N)
{
  __shared__ int loff[NRG];
  __shared__ int lcc[BB];
  const int rg = blockIdx.x, t = threadIdx.x;
  const int base = rbase[rg];
  for (int i = t; i < NRG; i += 256){
    int node = rg * NRG + i;
    if (node < N){
      int o = base + locoff[node];
      loff[i] = o;
      offsets[node] = o;
    } else loff[i] = 0;
  }
  for (int i = t; i < nb; i += 256) lcc[i] = cntc[i * nr + rg];
  __syncthreads();
  const int wv = t >> 6, lane = t & 63;
  for (int b = wv; b < nb; b += 4){
    const unsigned int* buf = bufc + ((size_t)b * nr + rg) * cap;
    int cnt = lcc[b];
    for (int i = lane; i < cnt; i += 64){
      unsigned int v = buf[i];
      int p = atomicAdd(&loff[v & 511], 1);   // LDS atomic
      csr_src[p] = (int)(v >> 9);
    }
  }
}

// --- pack layer-0: XH[n][j] = dinv[n]*(x, h) fp16 ---
__global__ void pack0_k(const float* __restrict__ X, const float* __restrict__ H,
                        const float* __restrict__ dinv, __half2* __restrict__ XH, int total){
  int i = blockIdx.x * 256 + threadIdx.x;
  if (i < total){
    float dv = dinv[i >> 6];
    __half2 v;
    v.x = __float2half_rn(dv * X[i]);
    v.y = __float2half_rn(dv * H[i]);
    XH[i] = v;
  }
}

// --- pack weights into MFMA B-fragment order + fused biases (see R8) ---
__global__ void packb_k(const float* __restrict__ Wxz, const float* __restrict__ Whz,
                        const float* __restrict__ Wxr, const float* __restrict__ Whr,
                        const float* __restrict__ Wxh, const float* __restrict__ Whh,
                        const float* __restrict__ bxz, const float* __restrict__ bhz,
                        const float* __restrict__ bxr, const float* __restrict__ bhr,
                        const float* __restrict__ bxh, const float* __restrict__ bhh,
                        _Float16* __restrict__ Bg, _Float16* __restrict__ Bo,
                        float* __restrict__ biasg, int L){
  const int PER = 24576 + 4096 + 192;
  int tid = blockIdx.x * 256 + threadIdx.x;
  if (tid >= L * PER) return;
  int l = tid / PER, r = tid % PER;
  if (r < 24576){
    int q = r;
    int s = q & 7, lane = (q >> 3) & 63, ks = (q >> 9) & 3, jt = q >> 11;
    int k = ks * 32 + (lane >> 4) * 8 + s;
    int b = jt >> 2;
    int j = (jt & 3) * 16 + (lane & 15);
    const float* Wx = (b == 0) ? Wxz : (b == 1) ? Wxr : Wxh;
    const float* Wh = (b == 0) ? Whz : Whr;
    float v;
    if (k < 64) v = Wx[(size_t)l * 4096 + k * 64 + j];
    else        v = (b == 2) ? 0.0f : Wh[(size_t)l * 4096 + (k - 64) * 64 + j];
    Bg[(size_t)l * 24576 + q] = (_Float16)v;
  } else if (r < 24576 + 4096){
    int q = r - 24576;
    int s = q & 7, lane = (q >> 3) & 63, ks = (q >> 9) & 1, jt = q >> 10;
    int k = ks * 32 + (lane >> 4) * 8 + s;
    int j = jt * 16 + (lane & 15);
    Bo[(size_t)l * 4096 + q] = (_Float16)Whh[(size_t)l * 4096 + k * 64 + j];
  } else {
    int j = r - (24576 + 4096);
    int b = j >> 6, jj = j & 63;
    float v = (b == 0) ? bxz[l * 64 + jj] + bhz[l * 64 + jj]
            : (b == 1) ? bxr[l * 64 + jj] + bhr[l * 64 + jj]
                       : bxh[l * 64 + jj] + bhh[l * 64 + jj];
    biasg[l * 192 + j] = v;
  }
}

// --- aggregation of pre-scaled (x,h) rows, unroll 8 ---
__global__ void agg2_k(const __half2* __restrict__ XH,
                       const int* __restrict__ offsets, const int* __restrict__ src,
                       const float* __restrict__ dinv,
                       _Float16* __restrict__ AXAH, int N){
  int wid = (blockIdx.x * blockDim.x + threadIdx.x) >> 6;
  int lane = threadIdx.x & 63;
  if (wid >= N) return;
  float dv = dinv[wid];
  size_t me = (size_t)wid * DD + lane;
  float2 sf = __half22float2(XH[me]);
  float ax[8], ah[8];
  #pragma unroll
  for (int j = 0; j < 8; j++){ ax[j] = 0.0f; ah[j] = 0.0f; }
  int s0 = offsets[wid], s1 = offsets[wid + 1];
  int e = s0;
  for (; e + 8 <= s1; e += 8){
    int sn[8];
    float2 f[8];
    #pragma unroll
    for (int j = 0; j < 8; j++) sn[j] = src[e + j];
    #pragma unroll
    for (int j = 0; j < 8; j++) f[j] = __half22float2(XH[(size_t)sn[j] * DD + lane]);
    #pragma unroll
    for (int j = 0; j < 8; j++){
      ax[j] += f[j].x;
      ah[j] += f[j].y;
    }
  }
  for (; e < s1; ++e){
    float2 fa = __half22float2(XH[(size_t)src[e] * DD + lane]);
    ax[0] += fa.x;
    ah[0] += fa.y;
  }
  float axs = ((ax[0] + ax[1]) + (ax[2] + ax[3])) + ((ax[4] + ax[5]) + (ax[6] + ax[7]));
  float ahs = ((ah[0] + ah[1]) + (ah[2] + ah[3])) + ((ah[4] + ah[5]) + (ah[6] + ah[7]));
  size_t o = (size_t)wid * 128 + lane;
  AXAH[o]      = (_Float16)(dv * (axs + 2.0f * sf.x));
  AXAH[o + 64] = (_Float16)(dv * (ahs + 2.0f * sf.y));
}

// --- aggregation of pre-scaled r*h rows, unroll 8 ---
__global__ void agg1_k(const _Float16* __restrict__ RH,
                       const int* __restrict__ offsets, const int* __restrict__ src,
                       const float* __restrict__ dinv,
                       _Float16* __restrict__ Arh, int N){
  int wid = (blockIdx.x * blockDim.x + threadIdx.x) >> 6;
  int lane = threadIdx.x & 63;
  if (wid >= N) return;
  float dv = dinv[wid];
  size_t me = (size_t)wid * DD + lane;
  float selfv = (float)RH[me];
  float ax[8];
  #pragma unroll
  for (int j = 0; j < 8; j++) ax[j] = 0.0f;
  int s0 = offsets[wid], s1 = offsets[wid + 1];
  int e = s0;
  for (; e + 8 <= s1; e += 8){
    int sn[8];
    float f[8];
    #pragma unroll
    for (int j = 0; j < 8; j++) sn[j] = src[e + j];
    #pragma unroll
    for (int j = 0; j < 8; j++) f[j] = (float)RH[(size_t)sn[j] * DD + lane];
    #pragma unroll
    for (int j = 0; j < 8; j++) ax[j] += f[j];
  }
  for (; e < s1; ++e){
    ax[0] += (float)RH[(size_t)src[e] * DD + lane];
  }
  float axs = ((ax[0] + ax[1]) + (ax[2] + ax[3])) + ((ax[4] + ax[5]) + (ax[6] + ax[7]));
  Arh[me] = (_Float16)(dv * (axs + 2.0f * selfv));
}

// ---------------------------------------------------------------------------
// MFMA gate kernel v5: C(N x 192) = AXAH @ Bg + bias.
// No fp32 Hh read: dinv*h comes from XH[].y (fp16); h = XH.y * rdinv.
//   rhb = XH.y * sigmoid(r)        (pre-scaled for agg1, no extra scale)
//   zh  = z * XH.y * rdinv         (= z*h)
// rhb staged through padded LDS -> coalesced 2KB wave stores (was 96 scalar
// 2B stores with 2x write amplification).
// zb/zh/t1 in wave-interleaved frag layout (coalesced, consumed by outm).
// ---------------------------------------------------------------------------
__global__ __launch_bounds__(256) void gatem_k(
    const _Float16* __restrict__ AXAH, const __half2* __restrict__ XH,
    const float* __restrict__ rdinv,
    const _Float16* __restrict__ Bg, const float* __restrict__ biasg,
    _Float16* __restrict__ zbf, _Float16* __restrict__ zhf_g,
    _Float16* __restrict__ rhb, _Float16* __restrict__ t1f, int N)
{
  __shared__ _Float16 lds_rh[4][16 * 68];
  const int lane = threadIdx.x & 63;
  const int wv   = threadIdx.x >> 6;
  const long nbase = ((long)blockIdx.x * 4 + wv) * 32;
  if (nbase >= N) return;
  const int m  = lane & 15;
  const int kb = lane >> 4;

  f32x4 acc[2][12];
  #pragma unroll
  for (int jt = 0; jt < 12; jt++){
    float bv = biasg[jt * 16 + m];
    f32x4 b4 = {bv, bv, bv, bv};
    acc[0][jt] = b4;
    acc[1][jt] = b4;
  }

  #pragma unroll 1
  for (int ks = 0; ks < 4; ks++){
    f16x8 af0, af1;
    {
      long r0 = nbase + m;           if (r0 >= N) r0 = N - 1;
      long r1 = nbase + 16 + m;      if (r1 >= N) r1 = N - 1;
      af0 = *(const f16x8*)(AXAH + (size_t)r0 * 128 + ks * 32 + kb * 8);
      af1 = *(const f16x8*)(AXAH + (size_t)r1 * 128 + ks * 32 + kb * 8);
    }
    #pragma unroll
    for (int jt = 0; jt < 12; jt++){
      f16x8 bf = *(const f16x8*)(Bg + ((size_t)(jt * 4 + ks) * 64 + lane) * 8);
      acc[0][jt] = __builtin_amdgcn_mfma_f32_16x16x32_f16(af0, bf, acc[0][jt], 0, 0, 0);
      acc[1][jt] = __builtin_amdgcn_mfma_f32_16x16x32_f16(af1, bf, acc[1][jt], 0, 0, 0);
    }
  }

  const int rl2 = lane >> 2;          // 0..15
  const int c0  = (lane & 3) * 16;    // 0,16,32,48

  _Float16 zf[32], tf[32], zhf[32];
  #pragma unroll
  for (int mt = 0; mt < 2; mt++){
    #pragma unroll
    for (int i = 0; i < 4; i++){
      long row = nbase + mt * 16 + kb * 4 + i;
      long rc = row < N ? row : N - 1;
      float rdv = rdinv[rc];
      const int rl = kb * 4 + i;
      #pragma unroll
      for (int jq = 0; jq < 4; jq++){
        int j = jq * 16 + m;
        size_t o = (size_t)rc * 64 + j;
        float hpre = __half2float(XH[o].y);   // = dinv*h (fp16)
        float z  = 1.0f / (1.0f + __expf(-acc[mt][jq][i]));
        float rr = 1.0f / (1.0f + __expf(-acc[mt][4 + jq][i]));
        const int idx = mt * 16 + jq * 4 + i;
        zf[idx]  = (_Float16)z;
        zhf[idx] = (_Float16)(z * hpre * rdv);
        tf[idx]  = (_Float16)acc[mt][8 + jq][i];
        lds_rh[wv][rl * 68 + j] = (_Float16)(hpre * rr);
      }
    }
    // coalesced rhb store from LDS (wave-synchronous)
    long grow = nbase + mt * 16 + rl2;
    if (grow < N){
      #pragma unroll
      for (int q = 0; q < 2; q++)
        *(f16x8*)(rhb + grow * 64 + c0 + q * 8) =
            *(f16x8*)&lds_rh[wv][rl2 * 68 + c0 + q * 8];
    }
  }

  const size_t fo = ((size_t)(blockIdx.x * 4 + wv)) * 2048 + (size_t)lane * 8;
  #pragma unroll
  for (int q = 0; q < 4; q++){
    *(f16x8*)(zbf   + fo + q * 512) = *(f16x8*)&zf[8 * q];
    *(f16x8*)(t1f   + fo + q * 512) = *(f16x8*)&tf[8 * q];
    *(f16x8*)(zhf_g + fo + q * 512) = *(f16x8*)&zhf[8 * q];
  }
}

// ---------------------------------------------------------------------------
// MFMA output kernel v4: acc = t1(frag) + Arh @ Bo; ho = zh + (1-z)*tanh(acc).
// Frag loads wave-interleaved (coalesced). Epilogue via padded LDS (stride 65)
// -> coalesced float4 o1/o2 writes; XHnext packed coalesced. Wave-synchronous
// LDS (no barrier: early-exited waves make __syncthreads unsafe).
// ---------------------------------------------------------------------------
__global__ __launch_bounds__(256) void outm_k(
    const _Float16* __restrict__ Arh, const _Float16* __restrict__ t1f,
    const _Float16* __restrict__ zbf, const _Float16* __restrict__ zhf_g,
    const float* __restrict__ dinv,
    const _Float16* __restrict__ Bo,
    float* __restrict__ o1, float* __restrict__ o2,
    const float* __restrict__ hNext, __half2* __restrict__ XHnext,
    int doPack, int N)
{
  __shared__ float lds_os[4][16 * 65];
  const int lane = threadIdx.x & 63;
  const int wv   = threadIdx.x >> 6;
  const long nbase = ((long)blockIdx.x * 4 + wv) * 32;
  if (nbase >= N) return;
  const int m  = lane & 15;
  const int kb = lane >> 4;
  const size_t fo = ((size_t)(blockIdx.x * 4 + wv)) * 2048 + (size_t)lane * 8;

  _Float16 tf[32];
  #pragma unroll
  for (int q = 0; q < 4; q++)
    *(f16x8*)&tf[8 * q] = *(const f16x8*)(t1f + fo + q * 512);

  f32x4 acc[2][4];
  #pragma unroll
  for (int mt = 0; mt < 2; mt++)
    #pragma unroll
    for (int jt = 0; jt < 4; jt++)
      #pragma unroll
      for (int i = 0; i < 4; i++)
        acc[mt][jt][i] = (float)tf[mt * 16 + jt * 4 + i];

  #pragma unroll
  for (int ks = 0; ks < 2; ks++){
    f16x8 af0, af1;
    {
      long r0 = nbase + m;           if (r0 >= N) r0 = N - 1;
      long r1 = nbase + 16 + m;      if (r1 >= N) r1 = N - 1;
      af0 = *(const f16x8*)(Arh + (size_t)r0 * 64 + ks * 32 + kb * 8);
      af1 = *(const f16x8*)(Arh + (size_t)r1 * 64 + ks * 32 + kb * 8);
    }
    #pragma unroll
    for (int jt = 0; jt < 4; jt++){
      f16x8 bf = *(const f16x8*)(Bo + ((size_t)(jt * 2 + ks) * 64 + lane) * 8);
      acc[0][jt] = __builtin_amdgcn_mfma_f32_16x16x32_f16(af0, bf, acc[0][jt], 0, 0, 0);
      acc[1][jt] = __builtin_amdgcn_mfma_f32_16x16x32_f16(af1, bf, acc[1][jt], 0, 0, 0);
    }
  }

  _Float16 zf[32], zhf[32];
  #pragma unroll
  for (int q = 0; q < 4; q++){
    *(f16x8*)&zf[8 * q]  = *(const f16x8*)(zbf   + fo + q * 512);
    *(f16x8*)&zhf[8 * q] = *(const f16x8*)(zhf_g + fo + q * 512);
  }

  const int rl2 = lane >> 2;          // 0..15
  const int c0  = (lane & 3) * 16;    // 0,16,32,48

  #pragma unroll
  for (int mt = 0; mt < 2; mt++){
    // compute ho into LDS tile (frag positions)
    #pragma unroll
    for (int i = 0; i < 4; i++){
      const int rl = kb * 4 + i;
      #pragma unroll
      for (int jt = 0; jt < 4; jt++){
        const int idx = mt * 16 + jt * 4 + i;
        float e  = __expf(2.0f * acc[mt][jt][i]);
        float ht = 1.0f - 2.0f / (e + 1.0f);
        float z  = (float)zf[idx];
        lds_os[wv][rl * 65 + jt * 16 + m] = (float)zhf[idx] + (1.0f - z) * ht;
      }
    }
    // coalesced writes from LDS (wave-synchronous)
    long grow = nbase + mt * 16 + rl2;
    bool vr = grow < N;
    long gc = vr ? grow : N - 1;
    #pragma unroll
    for (int q = 0; q < 4; q++){
      float4 v = *(float4*)&lds_os[wv][rl2 * 65 + c0 + q * 4];
      if (vr){
        *(float4*)(o1 + gc * 64 + c0 + q * 4) = v;
        *(float4*)(o2 + gc * 64 + c0 + q * 4) = v;
      }
    }
    if (doPack && vr){
      float dvr = dinv[gc];
      #pragma unroll
      for (int q = 0; q < 4; q++){
        float4 hov = *(float4*)&lds_os[wv][rl2 * 65 + c0 + q * 4];
        float4 hnv = *(const float4*)(hNext + gc * 64 + c0 + q * 4);
        __half2 tmp[4];
        tmp[0].x = __float2half_rn(dvr * hov.x); tmp[0].y = __float2half_rn(dvr * hnv.x);
        tmp[1].x = __float2half_rn(dvr * hov.y); tmp[1].y = __float2half_rn(dvr * hnv.y);
        tmp[2].x = __float2half_rn(dvr * hov.z); tmp[2].y = __float2half_rn(dvr * hnv.z);
        tmp[3].x = __float2half_rn(dvr * hov.w); tmp[3].y = __float2half_rn(dvr * hnv.w);
        *(float4*)(XHnext + gc * 64 + c0 + q * 4) = *(float4*)tmp;
      }
    }
  }
}

extern "C" void kernel_launch(void* const* d_in, const int* in_sizes, int n_in,
                              void* d_out, int out_size, void* d_ws, size_t ws_size,
                              hipStream_t stream){
  const float* inp = (const float*)d_in[0];
  const float* h   = (const float*)d_in[1];
  const int*   edg = (const int*)d_in[2];
  const float* Wxz = (const float*)d_in[3];
  const float* Whz = (const float*)d_in[4];
  const float* Wxr = (const float*)d_in[5];
  const float* Whr = (const float*)d_in[6];
  const float* Wxh = (const float*)d_in[7];
  const float* Whh = (const float*)d_in[8];
  const float* bxz = (const float*)d_in[9];
  const float* bhz = (const float*)d_in[10];
  const float* bxr = (const float*)d_in[11];
  const float* bhr = (const float*)d_in[12];
  const float* bxh = (const float*)d_in[13];
  const float* bhh = (const float*)d_in[14];
  float* out = (float*)d_out;

  const int ND = in_sizes[0];
  const int N  = ND / DD;
  const int E  = in_sizes[2] / 2;
  const int L  = in_sizes[1] / ND;

  const int nr  = divup(N, NRG);                 // ranges (196 @ N=100K)
  const int per = divup(E, BB);                  // edges per bin block
  const int cap = (per / nr) * 3 + 64;           // sub-buffer capacity (~3x mean)
  const int mBlocks = divup(N, 128);             // MFMA kernels: 4 waves x 32 nodes

  char* p = (char*)d_ws;
  auto alloc = [&](size_t bytes) -> void* {
    void* r = (void*)p;
    p += ((bytes + 255) / 256) * 256;
    return r;
  };
  auto a256 = [](size_t b) -> size_t { return ((b + 255) / 256) * 256; };

  int*      offsets = (int*)alloc((size_t)(N + 1) * 4);
  int*      locoff  = (int*)alloc((size_t)N * 4);
  int*      rtot    = (int*)alloc(256 * 4);
  int*      rbase   = (int*)alloc(256 * 4);
  float*    dinv    = (float*)alloc((size_t)N * 4);
  float*    rdinv   = (float*)alloc((size_t)N * 4);
  int*      cntc    = (int*)alloc((size_t)BB * nr * 4);
  int*      cntr    = (int*)alloc((size_t)BB * nr * 4);
  int*      csr_src = (int*)alloc((size_t)E * 4);
  __half2*  XH      = (__half2*)alloc((size_t)ND * 4);     // dinv-scaled (x,h)
  _Float16* Bg      = (_Float16*)alloc((size_t)L * 24576 * 2);
  _Float16* Bo      = (_Float16*)alloc((size_t)L * 4096 * 2);
  float*    biasg   = (float*)alloc((size_t)L * 192 * 4);

  // overlay: {bufc|bufr} (CSR build) reuses {AXAH|Arh|rhb|zbf|t1f|zhf} (layers)
  size_t bufc_b  = a256((size_t)BB * nr * cap * 4);
  size_t bufr_b  = a256((size_t)BB * nr * cap * 2);
  size_t axah_b  = a256((size_t)N * 128 * 2);
  size_t nd2_b   = a256((size_t)ND * 2);
  size_t frag_b  = a256((size_t)mBlocks * 4 * 2048 * 2);   // wave-interleaved frag buf
  size_t ov_b    = axah_b + 2 * nd2_b + 3 * frag_b;
  if (bufc_b + bufr_b > ov_b) ov_b = bufc_b + bufr_b;
  char* ov = (char*)alloc(ov_b);
  unsigned int*   bufc = (unsigned int*)ov;
  unsigned short* bufr = (unsigned short*)(ov + bufc_b);
  _Float16* AXAH = (_Float16*)ov;
  _Float16* Arh  = (_Float16*)(ov + axah_b);
  _Float16* rhb  = (_Float16*)(ov + axah_b + nd2_b);
  _Float16* zbf  = (_Float16*)(ov + axah_b + 2 * nd2_b);
  _Float16* t1f  = (_Float16*)(ov + axah_b + 2 * nd2_b + frag_b);
  _Float16* zhf  = (_Float16*)(ov + axah_b + 2 * nd2_b + 2 * frag_b);

  // --- CSR build: bin -> hist+local-scan -> range scan -> scatter ---
  bin_k<<<BB, 256, 2 * nr * 4, stream>>>(edg, E, per, nr, cap, bufc, bufr, cntc, cntr);
  cnt2b_k<<<nr, 256, 0, stream>>>(bufc, bufr, cntc, cntr, BB, nr, cap,
                                  locoff, rtot, dinv, rdinv, N);
  rscan_k<<<1, 256, 0, stream>>>(rtot, rbase, offsets, nr, E, N);
  scat_k<<<nr, 256, 0, stream>>>(bufc, cntc, BB, nr, cap, locoff, rbase,
                                 offsets, csr_src, N);

  pack0_k<<<divup(ND, 256), 256, 0, stream>>>(inp, h, dinv, XH, ND);
  {
    const int PER = 24576 + 4096 + 192;
    packb_k<<<divup(L * PER, 256), 256, 0, stream>>>(
        Wxz, Whz, Wxr, Whr, Wxh, Whh,
        bxz, bhz, bxr, bhr, bxh, bhh, Bg, Bo, biasg, L);
  }

  const int aggBlocks = divup(N, 4);     // 4 waves (nodes) per 256-thread block

  for (int l = 0; l < L; l++){
    agg2_k<<<aggBlocks, 256, 0, stream>>>(XH, offsets, csr_src, dinv, AXAH, N);
    gatem_k<<<mBlocks, 256, 0, stream>>>(AXAH, XH, rdinv,
        Bg + (size_t)l * 24576, biasg + (size_t)l * 192, zbf, zhf, rhb, t1f, N);
    agg1_k<<<aggBlocks, 256, 0, stream>>>(rhb, offsets, csr_src, dinv, Arh, N);
    const int doPack = (l + 1 < L);
    outm_k<<<mBlocks, 256, 0, stream>>>(Arh, t1f, zbf, zhf, dinv,
        Bo + (size_t)l * 4096,
        out + (size_t)l * ND, out + (size_t)L * ND + (size_t)l * ND,
        h + (size_t)(l + 1 < L ? l + 1 : l) * ND, XH, doPack, N);
  }
}